// Round 7
// baseline (1147.313 us; speedup 1.0000x reference)
//
#include <hip/hip_runtime.h>
#include <hip/hip_bf16.h>
#include <stdint.h>

// CubicModel: out = feats(feats(x)@W0^T + b0)@W1^T + b1
// feats(v) = [v, v_i*v_j (i<=j), v^3], d=512, K=132352
//
// R7: kill quad-staging divergence + expose no X-load latency.
//     - block-uniform window classification (kw is uniform): single-row
//       fast path / branchless 2-segment select / rare generic tail
//     - T14 split: stage_issue (loads only) BEFORE MFMA, stage_write after
//     (R6: VALUBusy 32% incl. divergent double-execution of the wrap walk;
//      X loads for t+1 issued after MFMA -> latency exposed.)

#define D_IN      512
#define BATCH     512
#define K_TOT     132352
#define QUAD_BASE 512
#define CUBE_BASE 131840
#define BN        128
#define BK        64          // LDS row = 128 B

typedef __attribute__((ext_vector_type(8))) __bf16 bf16x8;
typedef __attribute__((ext_vector_type(4))) float  f32x4;

__device__ __forceinline__ bf16x8 pack8(float a0, float a1, float a2, float a3,
                                        float a4, float a5, float a6, float a7) {
    bf16x8 r;
    r[0] = (__bf16)a0; r[1] = (__bf16)a1; r[2] = (__bf16)a2; r[3] = (__bf16)a3;
    r[4] = (__bf16)a4; r[5] = (__bf16)a5; r[6] = (__bf16)a6; r[7] = (__bf16)a7;
    return r;
}

// quad feature index: q -> (i,j), i<=j<512, q = i*(1025-i)/2 + (j-i)
__device__ __forceinline__ void decode_quad(int q, int& oi, int& oj) {
    // disc = 1050625-8q = (1025-2i)^2 at row starts; both < 2^24 -> exact
    float s = sqrtf((float)(1050625 - 8 * q));
    int i = (int)((1025.0f - s) * 0.5f);
    i = i < 0 ? 0 : (i > 511 ? 511 : i);
    while (i < 511 && (i + 1) * (1025 - (i + 1)) / 2 <= q) ++i;
    while (i > 0 && i * (1025 - i) / 2 > q) --i;
    oi = i; oj = i + (q - i * (1025 - i) / 2);
}

// staged raw loads for one 64-wide window (thread: chunk c of 4 batch rows)
struct Stg {
    float4 va[4], vb[4];     // raw 8 floats per p-row
    float  xi[4], xi1[4];    // row scales (quad modes)
    int    s1;               // segment-A length (mode 3)
    int    mode;             // 0 lin, 1 cube, 2 quad-1row, 3 quad-seg, 4 generic
};

// ---- phase 1: issue loads only (no arithmetic on loaded data -> no wait) ----
__device__ __forceinline__ void stage_issue(const float* __restrict__ X,
                                            int kw, int tid, Stg& st)
{
    const int c  = tid & 7;
    const int r0 = tid >> 3;
    const float* const xr = X + (size_t)r0 * D_IN;
    const int k = kw + c * 8;

    if (kw < QUAD_BASE) {                       // linear window
        st.mode = 0;
        #pragma unroll
        for (int p = 0; p < 4; ++p) {
            const float* row = xr + (size_t)p * (128 * D_IN);
            st.va[p] = *(const float4*)(row + k);
            st.vb[p] = *(const float4*)(row + k + 4);
        }
    } else if (kw >= CUBE_BASE) {               // cube window
        st.mode = 1;
        const int tt = k - CUBE_BASE;
        #pragma unroll
        for (int p = 0; p < 4; ++p) {
            const float* row = xr + (size_t)p * (128 * D_IN);
            st.va[p] = *(const float4*)(row + tt);
            st.vb[p] = *(const float4*)(row + tt + 4);
        }
    } else {                                    // quad window (block-uniform cls)
        const int qw = kw - QUAD_BASE;
        int iw, jw; decode_quad(qw, iw, jw);
        if (jw + 63 <= 511) {                   // whole window inside row iw
            st.mode = 2;
            const int j0 = jw + c * 8;
            #pragma unroll
            for (int p = 0; p < 4; ++p) {
                const float* row = xr + (size_t)p * (128 * D_IN);
                st.xi[p] = row[iw];
                st.va[p] = *(const float4*)(row + j0);
                st.vb[p] = *(const float4*)(row + j0 + 4);
            }
        } else {
            int ie, je; decode_quad(qw + 63, ie, je);
            if (ie <= 504) {                    // all rows in window have len>=8
                st.mode = 3;                    // <=1 boundary per 8-run
                int i0, j0; decode_quad(qw + c * 8, i0, j0);
                const int s1   = 512 - j0;      // elems in segment A (may be >=8)
                const int off1 = i0 + j0 - 511; // segB idx base: off1+e >= i0+1
                st.s1 = s1;
                const int x0 = (0 < s1 ? j0 : off1) + 0;
                const int x1 = (1 < s1 ? j0 : off1) + 1;
                const int x2 = (2 < s1 ? j0 : off1) + 2;
                const int x3 = (3 < s1 ? j0 : off1) + 3;
                const int x4 = (4 < s1 ? j0 : off1) + 4;
                const int x5 = (5 < s1 ? j0 : off1) + 5;
                const int x6 = (6 < s1 ? j0 : off1) + 6;
                const int x7 = (7 < s1 ? j0 : off1) + 7;
                #pragma unroll
                for (int p = 0; p < 4; ++p) {
                    const float* row = xr + (size_t)p * (128 * D_IN);
                    st.xi[p]  = row[i0];
                    st.xi1[p] = row[i0 + 1];    // i0<=504 -> safe
                    st.va[p].x = row[x0]; st.va[p].y = row[x1];
                    st.va[p].z = row[x2]; st.va[p].w = row[x3];
                    st.vb[p].x = row[x4]; st.vb[p].y = row[x5];
                    st.vb[p].z = row[x6]; st.vb[p].w = row[x7];
                }
            } else {
                st.mode = 4;                    // one tail window/layer: at write
            }
        }
    }
}

// ---- phase 2: arithmetic + pack + swizzled ds_write ----
__device__ __forceinline__ void stage_write(uint8_t* __restrict__ Ab,
                                            const float* __restrict__ X,
                                            int kw, int tid, const Stg& st)
{
    const int c  = tid & 7;
    const int r0 = tid >> 3;
    uint8_t* const wp0 = Ab + (size_t)r0 * 128 + (uint32_t)((c ^ (r0 & 7)) * 16);

    if (st.mode == 0) {
        #pragma unroll
        for (int p = 0; p < 4; ++p)
            *(bf16x8*)(wp0 + p * 16384) = pack8(
                st.va[p].x, st.va[p].y, st.va[p].z, st.va[p].w,
                st.vb[p].x, st.vb[p].y, st.vb[p].z, st.vb[p].w);
    } else if (st.mode == 1) {
        #pragma unroll
        for (int p = 0; p < 4; ++p) {
            float4 a = st.va[p], b = st.vb[p];
            *(bf16x8*)(wp0 + p * 16384) = pack8(
                a.x * a.x * a.x, a.y * a.y * a.y, a.z * a.z * a.z, a.w * a.w * a.w,
                b.x * b.x * b.x, b.y * b.y * b.y, b.z * b.z * b.z, b.w * b.w * b.w);
        }
    } else if (st.mode == 2) {
        #pragma unroll
        for (int p = 0; p < 4; ++p) {
            const float xi = st.xi[p];
            *(bf16x8*)(wp0 + p * 16384) = pack8(
                xi * st.va[p].x, xi * st.va[p].y, xi * st.va[p].z, xi * st.va[p].w,
                xi * st.vb[p].x, xi * st.vb[p].y, xi * st.vb[p].z, xi * st.vb[p].w);
        }
    } else if (st.mode == 3) {
        const int s1 = st.s1;
        #pragma unroll
        for (int p = 0; p < 4; ++p) {
            const float xa = st.xi[p], xb = st.xi1[p];
            *(bf16x8*)(wp0 + p * 16384) = pack8(
                (0 < s1 ? xa : xb) * st.va[p].x, (1 < s1 ? xa : xb) * st.va[p].y,
                (2 < s1 ? xa : xb) * st.va[p].z, (3 < s1 ? xa : xb) * st.va[p].w,
                (4 < s1 ? xa : xb) * st.vb[p].x, (5 < s1 ? xa : xb) * st.vb[p].y,
                (6 < s1 ? xa : xb) * st.vb[p].z, (7 < s1 ? xa : xb) * st.vb[p].w);
        }
    } else {                                    // generic tail (rare)
        const int k = kw + c * 8;
        int i0, j0; decode_quad(k - QUAD_BASE, i0, j0);
        #pragma unroll 1
        for (int p = 0; p < 4; ++p) {
            const float* row = X + (size_t)(r0 + p * 128) * D_IN;
            int i = i0, j = j0;
            float xi = row[i];
            float v[8];
            #pragma unroll
            for (int e = 0; e < 8; ++e) {
                v[e] = xi * row[j];
                ++j;
                if (e < 7 && j == 512) { ++i; j = i; xi = row[i]; }  // guarded
            }
            *(bf16x8*)(wp0 + p * 16384) = pack8(v[0], v[1], v[2], v[3],
                                                v[4], v[5], v[6], v[7]);
        }
    }
}

// ---------------- fused GEMM ----------------
// C[512][ldc] += feats(X)[512][K] * W_f32[n][K]^T (+bias by ks==0 blocks)
// 1024 thr = 16 waves (8m x 2n), wave tile 64x64, mfma 16x16x32, acc 4x4.
// LDS: A0,A1 64KB each; B0,B1 16KB each = 160KB dynamic.
__global__ __launch_bounds__(1024, 1) void gemm_fused(
    const float* __restrict__ X,
    const float* __restrict__ W,
    float* __restrict__ C, int ldc,
    const float* __restrict__ bias, int split_steps)
{
    extern __shared__ uint8_t smem[];
    const int tid  = threadIdx.x;
    const int lane = tid & 63;
    const int wave = tid >> 6;
    const int wm   = wave >> 1;                // 0..7
    const int wn   = wave & 1;                 // 0..1
    const int n0   = blockIdx.x * BN;
    const int ks   = blockIdx.y;

    const int kbeg = ks * split_steps * BK;
    const int kend = min(K_TOT, kbeg + split_steps * BK);
    if (kbeg >= kend) return;                  // ks==0 always has work -> bias safe
    const int nt = (kend - kbeg) / BK;

    // B staging: thread -> (row=tid>>3, chunk=tid&7)
    const int brow   = tid >> 3;
    const int bchunk = tid & 7;
    const float* const wsrc = W + (size_t)(n0 + brow) * K_TOT + bchunk * 8;
    const uint32_t boff = (uint32_t)brow * 128 + (uint32_t)((bchunk ^ (brow & 7)) * 16);

    // ---- prologue: tile 0 into buf0 ----
    Stg st;
    stage_issue(X, kbeg, tid, st);
    {
        float4 w0 = *(const float4*)(wsrc + kbeg);
        float4 w1 = *(const float4*)(wsrc + kbeg + 4);
        stage_write(smem, X, kbeg, tid, st);
        *(bf16x8*)(smem + 131072 + boff) =
            pack8(w0.x, w0.y, w0.z, w0.w, w1.x, w1.y, w1.z, w1.w);
    }
    __syncthreads();

    f32x4 acc[4][4] = {};
    const int fr = lane & 15;
    const int h  = lane >> 4;
    // frag addressing, hoisted: row&7 == lane&7 for every fragment ->
    // shared swizzled chunk offsets cs0 (s=0), cs1 = cs0^64 (s=1).
    uint32_t aoff[4], boffr[4];
    #pragma unroll
    for (int i = 0; i < 4; ++i) {
        aoff[i]  = (uint32_t)(wm * 64 + i * 16 + fr) * 128;
        boffr[i] = (uint32_t)(wn * 64 + i * 16 + fr) * 128;
    }
    const uint32_t cs0 = (uint32_t)((h ^ (lane & 7)) * 16);
    const uint32_t cs1 = cs0 ^ 64u;

    for (int t = 0; t < nt; ++t) {
        const uint32_t cur = (uint32_t)(t & 1);
        const uint8_t* const Ab = smem + cur * 65536u;
        const uint8_t* const Bb = smem + 131072u + cur * 16384u;
        const bool pre = (t + 1 < nt);
        const int kkn = kbeg + (t + 1) * BK;

        // ---- issue all of tile t+1's loads BEFORE the MFMA phase ----
        float4 nw0, nw1;
        if (pre) {
            stage_issue(X, kkn, tid, st);
            nw0 = *(const float4*)(wsrc + kkn);
            nw1 = *(const float4*)(wsrc + kkn + 4);
        }

        // ---- MFMA phase on tile t (hides the in-flight loads) ----
        __builtin_amdgcn_s_setprio(1);
        #pragma unroll
        for (int s = 0; s < 2; ++s) {
            const uint32_t cs = s ? cs1 : cs0;
            bf16x8 a[4];
            #pragma unroll
            for (int mf = 0; mf < 4; ++mf)
                a[mf] = *(const bf16x8*)(Ab + aoff[mf] + cs);
            #pragma unroll
            for (int nf = 0; nf < 4; ++nf) {
                bf16x8 b = *(const bf16x8*)(Bb + boffr[nf] + cs);
                #pragma unroll
                for (int mf = 0; mf < 4; ++mf)
                    acc[mf][nf] = __builtin_amdgcn_mfma_f32_16x16x32_bf16(a[mf], b, acc[mf][nf], 0, 0, 0);
            }
        }
        __builtin_amdgcn_s_setprio(0);

        // ---- arithmetic + writes for tile t+1 (waits land here) ----
        if (pre) {
            stage_write(smem + (cur ^ 1u) * 65536u, X, kkn, tid, st);
            *(bf16x8*)(smem + 131072u + (cur ^ 1u) * 16384u + boff) =
                pack8(nw0.x, nw0.y, nw0.z, nw0.w, nw1.x, nw1.y, nw1.z, nw1.w);
        }
        __syncthreads();
    }

    // epilogue: C/D layout col=lane&15, row=(lane>>4)*4+reg  [m89-verified]
    const bool dob = (ks == 0);
    const int rbase = wm * 64 + (lane >> 4) * 4;
    const int cbase = n0 + wn * 64 + (lane & 15);
    #pragma unroll
    for (int nf = 0; nf < 4; ++nf) {
        const int col = cbase + nf * 16;
        const float bv = dob ? bias[col] : 0.0f;
        #pragma unroll
        for (int mf = 0; mf < 4; ++mf) {
            const int row = rbase + mf * 16;
            #pragma unroll
            for (int r = 0; r < 4; ++r)
                unsafeAtomicAdd(&C[(size_t)(row + r) * ldc + col], acc[mf][nf][r] + bv);
        }
    }
}

// ---------------- host ----------------
extern "C" void kernel_launch(void* const* d_in, const int* in_sizes, int n_in,
                              void* d_out, int out_size, void* d_ws, size_t ws_size,
                              hipStream_t stream)
{
    const float* x  = (const float*)d_in[0];
    const float* W0 = (const float*)d_in[1];
    const float* b0 = (const float*)d_in[2];
    const float* W1 = (const float*)d_in[3];
    const float* b1 = (const float*)d_in[4];
    float* out = (float*)d_out;

    float* hbuf = (float*)d_ws;                        // [512][512]
    const size_t hbytes = (size_t)BATCH * 512 * 4;

    static int lds_set = 0;
    if (!lds_set) {    // host-side, idempotent, outside stream -> capture-safe
        hipFuncSetAttribute((const void*)gemm_fused,
                            hipFuncAttributeMaxDynamicSharedMemorySize, 163840);
        lds_set = 1;
    }

    hipMemsetAsync(hbuf, 0, hbytes, stream);
    hipMemsetAsync(out, 0, (size_t)out_size * 4, stream);

    const int TS = K_TOT / BK;                         // 2068 K-steps total

    // layer 0: h = feats(x) @ W0^T + b0     grid (4, 63) = 252 blocks
    {
        const int ss = 33;
        const int gy = (TS + ss - 1) / ss;             // 63
        gemm_fused<<<dim3(512 / BN, gy), 1024, 163840, stream>>>(
            x, W0, hbuf, 512, b0, ss);
    }
    // layer 1: out = feats(h) @ W1^T + b1   grid (2, 122) = 244 blocks
    {
        const int ss = 17;
        const int gy = (TS + ss - 1) / ss;             // 122
        gemm_fused<<<dim3(256 / BN, gy), 1024, 163840, stream>>>(
            hbuf, W1, out, 256, b1, ss);
    }
}

// Round 8
// 782.447 us; speedup vs baseline: 1.4663x; 1.4663x over previous
//
#include <hip/hip_runtime.h>
#include <hip/hip_bf16.h>
#include <stdint.h>

// CubicModel: out = feats(feats(x)@W0^T + b0)@W1^T + b1
// feats(v) = [v, v_i*v_j (i<=j), v^3], d=512, K=132352
//
// R8 = R6 (353us best) + bounded changes:
//  - depth-2 W prefetch held in regs (nwA=t+1, nwB=t+2) with RAW s_barrier
//    + counted s_waitcnt vmcnt(2) (R3-proven sequence) so W loads stay in
//    flight across the barrier (R6's __syncthreads drained them every step)
//  - divergence-free quad staging: block-uniform window class, branchless
//    2-segment select computed inline per-p (small live set -- NOT R7's
//    Stg-across-MFMA, which spilled: 1.05GB scratch writes)

#define D_IN      512
#define BATCH     512
#define K_TOT     132352
#define QUAD_BASE 512
#define CUBE_BASE 131840
#define BN        128
#define BK        64          // LDS row = 128 B

typedef __attribute__((ext_vector_type(8))) __bf16 bf16x8;
typedef __attribute__((ext_vector_type(4))) float  f32x4;

__device__ __forceinline__ bf16x8 pack8(float a0, float a1, float a2, float a3,
                                        float a4, float a5, float a6, float a7) {
    bf16x8 r;
    r[0] = (__bf16)a0; r[1] = (__bf16)a1; r[2] = (__bf16)a2; r[3] = (__bf16)a3;
    r[4] = (__bf16)a4; r[5] = (__bf16)a5; r[6] = (__bf16)a6; r[7] = (__bf16)a7;
    return r;
}

// quad feature index: q -> (i,j), i<=j<512, q = i*(1025-i)/2 + (j-i)
__device__ __forceinline__ void decode_quad(int q, int& oi, int& oj) {
    // disc = 1050625-8q = (1025-2i)^2 at row starts; both < 2^24 -> exact
    float s = sqrtf((float)(1050625 - 8 * q));
    int i = (int)((1025.0f - s) * 0.5f);
    i = i < 0 ? 0 : (i > 511 ? 511 : i);
    while (i < 511 && (i + 1) * (1025 - (i + 1)) / 2 <= q) ++i;
    while (i > 0 && i * (1025 - i) / 2 > q) --i;
    oi = i; oj = i + (q - i * (1025 - i) / 2);
}

// stage feats for window [kw,kw+64): thread -> chunk c=tid&7 of rows
// {r0, r0+128, r0+256, r0+384}. Block-uniform mode select (kw uniform);
// every path loads+computes+writes per-p immediately (small live set).
__device__ __forceinline__ void stage_A(const float* __restrict__ X,
                                        uint8_t* __restrict__ Ab,
                                        int kw, int tid) {
    const int c  = tid & 7;
    const int r0 = tid >> 3;
    const int k  = kw + c * 8;
    uint8_t* const wp0 = Ab + (size_t)r0 * 128 + (uint32_t)((c ^ (r0 & 7)) * 16);
    const float* const xr = X + (size_t)r0 * D_IN;

    if (kw < QUAD_BASE) {                      // linear window
        #pragma unroll 2
        for (int p = 0; p < 4; ++p) {
            const float* row = xr + (size_t)p * (128 * D_IN);
            float4 a = *(const float4*)(row + k);
            float4 b = *(const float4*)(row + k + 4);
            *(bf16x8*)(wp0 + p * 16384) = pack8(a.x, a.y, a.z, a.w, b.x, b.y, b.z, b.w);
        }
    } else if (kw >= CUBE_BASE) {              // cube window
        const int tt = k - CUBE_BASE;
        #pragma unroll 2
        for (int p = 0; p < 4; ++p) {
            const float* row = xr + (size_t)p * (128 * D_IN);
            float4 a = *(const float4*)(row + tt);
            float4 b = *(const float4*)(row + tt + 4);
            *(bf16x8*)(wp0 + p * 16384) = pack8(
                a.x * a.x * a.x, a.y * a.y * a.y, a.z * a.z * a.z, a.w * a.w * a.w,
                b.x * b.x * b.x, b.y * b.y * b.y, b.z * b.z * b.z, b.w * b.w * b.w);
        }
    } else {                                   // quad window
        const int qw = kw - QUAD_BASE;
        int iw, jw; decode_quad(qw, iw, jw);
        if (jw + 63 <= 511) {                  // whole window inside triu row iw
            const int j0 = jw + c * 8;
            #pragma unroll 2
            for (int p = 0; p < 4; ++p) {
                const float* row = xr + (size_t)p * (128 * D_IN);
                const float xi = row[iw];
                float4 a = *(const float4*)(row + j0);
                float4 b = *(const float4*)(row + j0 + 4);
                *(bf16x8*)(wp0 + p * 16384) = pack8(
                    xi * a.x, xi * a.y, xi * a.z, xi * a.w,
                    xi * b.x, xi * b.y, xi * b.z, xi * b.w);
            }
        } else {
            int ie, je; decode_quad(qw + 63, ie, je);
            if (ie <= 504) {                   // all touched rows have len>=8:
                                               // <=1 boundary per 8-run -> branchless
                int i0, j0; decode_quad(qw + c * 8, i0, j0);
                const int s1   = 512 - j0;     // elems in segment A
                const int off1 = i0 + j0 - 511;// segB index base (row i0+1)
                int xx[8];
                #pragma unroll
                for (int e = 0; e < 8; ++e) xx[e] = (e < s1 ? j0 : off1) + e;
                #pragma unroll 2
                for (int p = 0; p < 4; ++p) {
                    const float* row = xr + (size_t)p * (128 * D_IN);
                    const float xa = row[i0];
                    const float xb = row[i0 + 1];          // i0<=504 -> in bounds
                    *(bf16x8*)(wp0 + p * 16384) = pack8(
                        (0 < s1 ? xa : xb) * row[xx[0]], (1 < s1 ? xa : xb) * row[xx[1]],
                        (2 < s1 ? xa : xb) * row[xx[2]], (3 < s1 ? xa : xb) * row[xx[3]],
                        (4 < s1 ? xa : xb) * row[xx[4]], (5 < s1 ? xa : xb) * row[xx[5]],
                        (6 < s1 ? xa : xb) * row[xx[6]], (7 < s1 ? xa : xb) * row[xx[7]]);
                }
            } else {                           // generic tail (1 window per layer)
                int i0, j0; decode_quad(qw + c * 8, i0, j0);
                #pragma unroll 1
                for (int p = 0; p < 4; ++p) {
                    const float* row = xr + (size_t)p * (128 * D_IN);
                    int i = i0, j = j0;
                    float xi = row[i];
                    float v[8];
                    #pragma unroll
                    for (int e = 0; e < 8; ++e) {
                        v[e] = xi * row[j];
                        ++j;
                        if (e < 7 && j == 512) { ++i; j = i; xi = row[i]; }
                    }
                    *(bf16x8*)(wp0 + p * 16384) = pack8(v[0], v[1], v[2], v[3],
                                                        v[4], v[5], v[6], v[7]);
                }
            }
        }
    }
}

// ---------------- fused GEMM ----------------
// C[512][ldc] += feats(X)[512][K] * W_f32[n][K]^T (+bias by ks==0 blocks)
// 1024 thr = 16 waves (8m x 2n), wave tile 64x64, mfma 16x16x32, acc 4x4.
// LDS: A0,A1 64KB each; B0,B1 16KB each = 160KB dynamic.
__global__ __launch_bounds__(1024, 1) void gemm_fused(
    const float* __restrict__ X,
    const float* __restrict__ W,
    float* __restrict__ C, int ldc,
    const float* __restrict__ bias, int split_steps)
{
    extern __shared__ uint8_t smem[];
    const int tid  = threadIdx.x;
    const int lane = tid & 63;
    const int wave = tid >> 6;
    const int wm   = wave >> 1;                // 0..7
    const int wn   = wave & 1;                 // 0..1
    const int n0   = blockIdx.x * BN;
    const int ks   = blockIdx.y;

    const int kbeg = ks * split_steps * BK;
    const int kend = min(K_TOT, kbeg + split_steps * BK);
    if (kbeg >= kend) return;                  // ks==0 always has work -> bias safe
    const int nt = (kend - kbeg) / BK;

    // B staging: thread -> (row=tid>>3, chunk=tid&7)
    const int brow   = tid >> 3;
    const int bchunk = tid & 7;
    const float* const wsrc = W + (size_t)(n0 + brow) * K_TOT + bchunk * 8;
    const uint32_t boff = (uint32_t)brow * 128 + (uint32_t)((bchunk ^ (brow & 7)) * 16);

    // ---- prologue: tile 0 into buf0; start depth-2 W pipeline ----
    stage_A(X, smem, kbeg, tid);
    {
        float4 w0 = *(const float4*)(wsrc + kbeg);
        float4 w1 = *(const float4*)(wsrc + kbeg + 4);
        *(bf16x8*)(smem + 131072 + boff) =
            pack8(w0.x, w0.y, w0.z, w0.w, w1.x, w1.y, w1.z, w1.w);
    }
    float4 nwA0 = {}, nwA1 = {};
    if (nt > 1) {
        nwA0 = *(const float4*)(wsrc + kbeg + BK);
        nwA1 = *(const float4*)(wsrc + kbeg + BK + 4);
    }
    __syncthreads();

    f32x4 acc[4][4] = {};
    const int fr = lane & 15;
    const int h  = lane >> 4;
    // frag addressing, hoisted: row&7 == lane&7 for every fragment ->
    // shared swizzled chunk offsets cs0 (s=0), cs1 = cs0^64 (s=1).
    uint32_t aoff[4], boffr[4];
    #pragma unroll
    for (int i = 0; i < 4; ++i) {
        aoff[i]  = (uint32_t)(wm * 64 + i * 16 + fr) * 128;
        boffr[i] = (uint32_t)(wn * 64 + i * 16 + fr) * 128;
    }
    const uint32_t cs0 = (uint32_t)((h ^ (lane & 7)) * 16);
    const uint32_t cs1 = cs0 ^ 64u;

    for (int t = 0; t < nt; ++t) {
        const uint32_t cur = (uint32_t)(t & 1);
        const uint8_t* const Ab = smem + cur * 65536u;
        const uint8_t* const Bb = smem + 131072u + cur * 16384u;
        const bool pre  = (t + 1 < nt);
        const bool pre2 = (t + 2 < nt);

        // issue W(t+2) now; stays in flight across this iter's barrier
        float4 nwB0 = {}, nwB1 = {};
        if (pre2) {
            nwB0 = *(const float4*)(wsrc + kbeg + (t + 2) * BK);
            nwB1 = *(const float4*)(wsrc + kbeg + (t + 2) * BK + 4);
        }

        // ---- MFMA phase on tile t ----
        __builtin_amdgcn_s_setprio(1);
        #pragma unroll
        for (int s = 0; s < 2; ++s) {
            const uint32_t cs = s ? cs1 : cs0;
            bf16x8 a[4];
            #pragma unroll
            for (int mf = 0; mf < 4; ++mf)
                a[mf] = *(const bf16x8*)(Ab + aoff[mf] + cs);
            #pragma unroll
            for (int nf = 0; nf < 4; ++nf) {
                bf16x8 b = *(const bf16x8*)(Bb + boffr[nf] + cs);
                #pragma unroll
                for (int mf = 0; mf < 4; ++mf)
                    acc[mf][nf] = __builtin_amdgcn_mfma_f32_16x16x32_bf16(a[mf], b, acc[mf][nf], 0, 0, 0);
            }
        }
        __builtin_amdgcn_s_setprio(0);

        // ---- stage tile t+1 into the other buffers; consume nwA ----
        if (pre) {
            stage_A(X, smem + (cur ^ 1u) * 65536u, kbeg + (t + 1) * BK, tid);
            *(bf16x8*)(smem + 131072u + (cur ^ 1u) * 16384u + boff) =
                pack8(nwA0.x, nwA0.y, nwA0.z, nwA0.w, nwA1.x, nwA1.y, nwA1.z, nwA1.w);
            nwA0 = nwB0; nwA1 = nwB1;
        }

        // barrier: LDS writes visible; allow nwB's 2 loads to stay in flight
        asm volatile("s_waitcnt lgkmcnt(0)" ::: "memory");
        asm volatile("s_waitcnt vmcnt(2)" ::: "memory");
        __builtin_amdgcn_sched_barrier(0);
        __builtin_amdgcn_s_barrier();
        asm volatile("" ::: "memory");
    }

    // epilogue: C/D layout col=lane&15, row=(lane>>4)*4+reg  [m89-verified]
    const bool dob = (ks == 0);
    const int rbase = wm * 64 + (lane >> 4) * 4;
    const int cbase = n0 + wn * 64 + (lane & 15);
    #pragma unroll
    for (int nf = 0; nf < 4; ++nf) {
        const int col = cbase + nf * 16;
        const float bv = dob ? bias[col] : 0.0f;
        #pragma unroll
        for (int mf = 0; mf < 4; ++mf) {
            const int row = rbase + mf * 16;
            #pragma unroll
            for (int r = 0; r < 4; ++r)
                unsafeAtomicAdd(&C[(size_t)(row + r) * ldc + col], acc[mf][nf][r] + bv);
        }
    }
}

// ---------------- host ----------------
extern "C" void kernel_launch(void* const* d_in, const int* in_sizes, int n_in,
                              void* d_out, int out_size, void* d_ws, size_t ws_size,
                              hipStream_t stream)
{
    const float* x  = (const float*)d_in[0];
    const float* W0 = (const float*)d_in[1];
    const float* b0 = (const float*)d_in[2];
    const float* W1 = (const float*)d_in[3];
    const float* b1 = (const float*)d_in[4];
    float* out = (float*)d_out;

    float* hbuf = (float*)d_ws;                        // [512][512]
    const size_t hbytes = (size_t)BATCH * 512 * 4;

    static int lds_set = 0;
    if (!lds_set) {    // host-side, idempotent, outside stream -> capture-safe
        hipFuncSetAttribute((const void*)gemm_fused,
                            hipFuncAttributeMaxDynamicSharedMemorySize, 163840);
        lds_set = 1;
    }

    hipMemsetAsync(hbuf, 0, hbytes, stream);
    hipMemsetAsync(out, 0, (size_t)out_size * 4, stream);

    const int TS = K_TOT / BK;                         // 2068 K-steps total

    // layer 0: h = feats(x) @ W0^T + b0     grid (4, 63) = 252 blocks
    {
        const int ss = 33;
        const int gy = (TS + ss - 1) / ss;             // 63
        gemm_fused<<<dim3(512 / BN, gy), 1024, 163840, stream>>>(
            x, W0, hbuf, 512, b0, ss);
    }
    // layer 1: out = feats(h) @ W1^T + b1   grid (2, 122) = 244 blocks
    {
        const int ss = 17;
        const int gy = (TS + ss - 1) / ss;             // 122
        gemm_fused<<<dim3(256 / BN, gy), 1024, 163840, stream>>>(
            hbuf, W1, out, 256, b1, ss);
    }
}

// Round 9
// 537.683 us; speedup vs baseline: 2.1338x; 1.4552x over previous
//
#include <hip/hip_runtime.h>
#include <hip/hip_bf16.h>
#include <stdint.h>

// CubicModel: out = feats(feats(x)@W0^T + b0)@W1^T + b1
// feats(v) = [v, v_i*v_j (i<=j), v^3], d=512, K=132352
//
// R9: 2 blocks/CU. R6's phases serialized (all 16 waves lockstep between
//     barriers, 1 block/CU at 160KB LDS): step = Σ(VALU,LDS,L2,HBM,MFMA).
//     Restructure: 512 thr, BM=256, sbuf LDS 48KB, 2 barriers/step ->
//     two independent blocks co-resident; phases overlap (m114).
//     Staging code = R6 verbatim (known non-spilling). No W-prefetch regs
//     (JIT loads; latency covered by sibling block). R8 reverted (spill).

#define D_IN      512
#define BATCH     512
#define K_TOT     132352
#define QUAD_BASE 512
#define CUBE_BASE 131840
#define BM        256
#define BN        128
#define BK        64          // LDS row = 128 B

typedef __attribute__((ext_vector_type(8))) __bf16 bf16x8;
typedef __attribute__((ext_vector_type(4))) float  f32x4;

__device__ __forceinline__ bf16x8 pack8(float a0, float a1, float a2, float a3,
                                        float a4, float a5, float a6, float a7) {
    bf16x8 r;
    r[0] = (__bf16)a0; r[1] = (__bf16)a1; r[2] = (__bf16)a2; r[3] = (__bf16)a3;
    r[4] = (__bf16)a4; r[5] = (__bf16)a5; r[6] = (__bf16)a6; r[7] = (__bf16)a7;
    return r;
}

// quad feature index: q -> (i,j), i<=j<512, q = i*(1025-i)/2 + (j-i)
__device__ __forceinline__ void decode_quad(int q, int& oi, int& oj) {
    // disc = 1050625-8q = (1025-2i)^2 at row starts; both < 2^24 -> exact
    float s = sqrtf((float)(1050625 - 8 * q));
    int i = (int)((1025.0f - s) * 0.5f);
    i = i < 0 ? 0 : (i > 511 ? 511 : i);
    while (i < 511 && (i + 1) * (1025 - (i + 1)) / 2 <= q) ++i;
    while (i > 0 && i * (1025 - i) / 2 > q) --i;
    oi = i; oj = i + (q - i * (1025 - i) / 2);
}

// stage feats for window [kw,kw+64): thread -> chunk c=tid&7 of rows
// {r0, r0+64, r0+128, r0+192} of the 256-row m-tile (global row m0+...).
// Swizzled write offset is p-invariant (row&7 == r0&7). R6 codegen.
__device__ __forceinline__ void stage_A(const float* __restrict__ X, int m0,
                                        uint8_t* __restrict__ Ab,
                                        int kw, int tid) {
    const int c  = tid & 7;
    const int r0 = tid >> 3;                   // 0..63
    const int k  = kw + c * 8;
    uint8_t* const wp0 = Ab + (size_t)r0 * 128 + (uint32_t)((c ^ (r0 & 7)) * 16);
    const float* const xr = X + (size_t)(m0 + r0) * D_IN;

    if (kw < QUAD_BASE) {                      // linear window
        #pragma unroll 2
        for (int p = 0; p < 4; ++p) {
            const float* row = xr + (size_t)p * (64 * D_IN);
            float4 a = *(const float4*)(row + k);
            float4 b = *(const float4*)(row + k + 4);
            *(bf16x8*)(wp0 + p * 8192) = pack8(a.x, a.y, a.z, a.w, b.x, b.y, b.z, b.w);
        }
    } else if (kw >= CUBE_BASE) {              // cube window
        const int tt = k - CUBE_BASE;
        #pragma unroll 2
        for (int p = 0; p < 4; ++p) {
            const float* row = xr + (size_t)p * (64 * D_IN);
            float4 a = *(const float4*)(row + tt);
            float4 b = *(const float4*)(row + tt + 4);
            *(bf16x8*)(wp0 + p * 8192) = pack8(
                a.x * a.x * a.x, a.y * a.y * a.y, a.z * a.z * a.z, a.w * a.w * a.w,
                b.x * b.x * b.x, b.y * b.y * b.y, b.z * b.z * b.z, b.w * b.w * b.w);
        }
    } else {                                   // quad window
        const int qw = kw - QUAD_BASE;
        int iw, jw; decode_quad(qw, iw, jw);
        if (jw + 63 <= 511) {                  // whole window inside triu row iw
            const int j0 = jw + c * 8;
            #pragma unroll 2
            for (int p = 0; p < 4; ++p) {
                const float* row = xr + (size_t)p * (64 * D_IN);
                const float xi = row[iw];
                float4 a = *(const float4*)(row + j0);
                float4 b = *(const float4*)(row + j0 + 4);
                *(bf16x8*)(wp0 + p * 8192) = pack8(
                    xi * a.x, xi * a.y, xi * a.z, xi * a.w,
                    xi * b.x, xi * b.y, xi * b.z, xi * b.w);
            }
        } else {                               // row-crossing window (R6 path)
            int i0, j0; decode_quad(qw + c * 8, i0, j0);
            #pragma unroll 1
            for (int p = 0; p < 4; ++p) {
                const float* row = xr + (size_t)p * (64 * D_IN);
                int i = i0, j = j0;
                float xi = row[i];
                float v[8];
                #pragma unroll
                for (int e = 0; e < 8; ++e) {
                    v[e] = xi * row[j];
                    ++j;
                    if (e < 7 && j == 512) { ++i; j = i; xi = row[i]; }
                }
                *(bf16x8*)(wp0 + p * 8192) = pack8(v[0], v[1], v[2], v[3],
                                                   v[4], v[5], v[6], v[7]);
            }
        }
    }
}

// ---------------- fused GEMM ----------------
// C[m0:m0+256][ldc] += feats(X)[...][K] * W_f32[n][K]^T (+bias by ks==0)
// 512 thr = 8 waves (4m x 2n), wave tile 64x64, mfma 16x16x32, acc 4x4.
// LDS: A 32KB + B 16KB = 48KB static, single-buffered, 2 barriers/step.
__global__ __launch_bounds__(512, 4) void gemm_fused(
    const float* __restrict__ X,
    const float* __restrict__ W,
    float* __restrict__ C, int ldc,
    const float* __restrict__ bias, int split_steps)
{
    __shared__ uint8_t Asm[BM * 128];          // 32KB  [row][swizzled 16B chunk]
    __shared__ uint8_t Bsm[BN * 128];          // 16KB

    const int tid  = threadIdx.x;
    const int lane = tid & 63;
    const int wave = tid >> 6;                 // 0..7
    const int wm   = wave >> 1;                // 0..3 : rows wm*64
    const int wn   = wave & 1;                 // 0..1 : cols wn*64
    const int m0   = (blockIdx.x & 1) * BM;
    const int n0   = (blockIdx.x >> 1) * BN;
    const int ks   = blockIdx.y;

    const int kbeg = ks * split_steps * BK;
    const int kend = min(K_TOT, kbeg + split_steps * BK);
    if (kbeg >= kend) return;                  // ks==0 always has work -> bias safe
    const int nt = (kend - kbeg) / BK;

    // B staging: thread -> (row=tid>>2, quarter q=tid&3 -> chunks 2q,2q+1)
    const int brow = tid >> 2;                 // 0..127
    const int bq   = tid & 3;
    const float* const wsrc = W + (size_t)(n0 + brow) * K_TOT + bq * 16;
    uint8_t* const bw0 = Bsm + (size_t)brow * 128
                       + (uint32_t)(((2 * bq)     ^ (brow & 7)) * 16);
    uint8_t* const bw1 = Bsm + (size_t)brow * 128
                       + (uint32_t)(((2 * bq + 1) ^ (brow & 7)) * 16);

    f32x4 acc[4][4] = {};
    const int fr = lane & 15;
    const int h  = lane >> 4;
    // frag addressing, hoisted: row&7 == lane&7 for every fragment ->
    // shared swizzled chunk offsets cs0 (s=0), cs1 = cs0^64 (s=1).
    uint32_t aoff[4], boffr[4];
    #pragma unroll
    for (int i = 0; i < 4; ++i) {
        aoff[i]  = (uint32_t)(wm * 64 + i * 16 + fr) * 128;
        boffr[i] = (uint32_t)(wn * 64 + i * 16 + fr) * 128;
    }
    const uint32_t cs0 = (uint32_t)((h ^ (lane & 7)) * 16);
    const uint32_t cs1 = cs0 ^ 64u;

    for (int t = 0; t < nt; ++t) {
        const int kk = kbeg + t * BK;

        // ---- stage A (features) + B (W cast) into LDS ----
        stage_A(X, m0, Asm, kk, tid);
        {
            const float* wp = wsrc + kk;
            float4 w0 = *(const float4*)(wp);
            float4 w1 = *(const float4*)(wp + 4);
            float4 w2 = *(const float4*)(wp + 8);
            float4 w3 = *(const float4*)(wp + 12);
            *(bf16x8*)bw0 = pack8(w0.x, w0.y, w0.z, w0.w, w1.x, w1.y, w1.z, w1.w);
            *(bf16x8*)bw1 = pack8(w2.x, w2.y, w2.z, w2.w, w3.x, w3.y, w3.z, w3.w);
        }
        __syncthreads();                       // staging visible

        // ---- MFMA phase ----
        __builtin_amdgcn_s_setprio(1);
        #pragma unroll
        for (int s = 0; s < 2; ++s) {
            const uint32_t cs = s ? cs1 : cs0;
            bf16x8 a[4];
            #pragma unroll
            for (int mf = 0; mf < 4; ++mf)
                a[mf] = *(const bf16x8*)(Asm + aoff[mf] + cs);
            #pragma unroll
            for (int nf = 0; nf < 4; ++nf) {
                bf16x8 b = *(const bf16x8*)(Bsm + boffr[nf] + cs);
                #pragma unroll
                for (int mf = 0; mf < 4; ++mf)
                    acc[mf][nf] = __builtin_amdgcn_mfma_f32_16x16x32_bf16(a[mf], b, acc[mf][nf], 0, 0, 0);
            }
        }
        __builtin_amdgcn_s_setprio(0);
        __syncthreads();                       // reads done; next stage may overwrite
    }

    // epilogue: C/D layout col=lane&15, row=(lane>>4)*4+reg  [m89-verified]
    const bool dob = (ks == 0);
    const int rbase = m0 + wm * 64 + (lane >> 4) * 4;
    const int cbase = n0 + wn * 64 + (lane & 15);
    #pragma unroll
    for (int nf = 0; nf < 4; ++nf) {
        const int col = cbase + nf * 16;
        const float bv = dob ? bias[col] : 0.0f;
        #pragma unroll
        for (int mf = 0; mf < 4; ++mf) {
            const int row = rbase + mf * 16;
            #pragma unroll
            for (int r = 0; r < 4; ++r)
                unsafeAtomicAdd(&C[(size_t)(row + r) * ldc + col], acc[mf][nf][r] + bv);
        }
    }
}

// ---------------- host ----------------
extern "C" void kernel_launch(void* const* d_in, const int* in_sizes, int n_in,
                              void* d_out, int out_size, void* d_ws, size_t ws_size,
                              hipStream_t stream)
{
    const float* x  = (const float*)d_in[0];
    const float* W0 = (const float*)d_in[1];
    const float* b0 = (const float*)d_in[2];
    const float* W1 = (const float*)d_in[3];
    const float* b1 = (const float*)d_in[4];
    float* out = (float*)d_out;

    float* hbuf = (float*)d_ws;                        // [512][512]
    const size_t hbytes = (size_t)BATCH * 512 * 4;

    hipMemsetAsync(hbuf, 0, hbytes, stream);
    hipMemsetAsync(out, 0, (size_t)out_size * 4, stream);

    const int TS = K_TOT / BK;                         // 2068 K-steps total

    // layer 0: h = feats(x) @ W0^T + b0
    // grid.x: 8 = 2 m-blocks x 4 n-blocks; grid.y: 63 -> 504 blocks (~2/CU)
    {
        const int ss = 33;
        const int gy = (TS + ss - 1) / ss;             // 63
        gemm_fused<<<dim3(8, gy), 512, 0, stream>>>(
            x, W0, hbuf, 512, b0, ss);
    }
    // layer 1: out = feats(h) @ W1^T + b1
    // grid.x: 4 = 2 m-blocks x 2 n-blocks; grid.y: 122 -> 488 blocks (~2/CU)
    {
        const int ss = 17;
        const int gy = (TS + ss - 1) / ss;             // 122
        gemm_fused<<<dim3(4, gy), 512, 0, stream>>>(
            hbuf, W1, out, 256, b1, ss);
    }
}